// Round 10
// baseline (644.604 us; speedup 1.0000x reference)
//
#include <hip/hip_runtime.h>
#include <hip/hip_bf16.h>

// GAT 3-layer forward. N=50000, E=1.6M, H=4, D=32, C=47.
// Round 10: head-padded layer-2 layout (stride 48/head => single-head lane
// groups, no cndmask in agg), padded bf16 input (layer-0 gemm = short8 path),
// final log_softmax fused into layer-2 agg.
//
// ws: fs[N*192 bf16] hb16[N*128 bf16] xpad[N*128 bf16] el/er[N*4 f32]
//     rowptr cur col bsum boff flag  => ~53 MB.

using bf16 = __hip_bfloat16;
typedef __attribute__((ext_vector_type(8))) short short8;
typedef __attribute__((ext_vector_type(4))) float floatx4;

static constexpr int NN = 50000;
static constexpr int H  = 4;

__device__ __forceinline__ float b2f(bf16 x) { return __bfloat162float(x); }
__device__ __forceinline__ float ldx(const void* p, size_t i, bool bf) {
    return bf ? __bfloat162float(((const bf16*)p)[i]) : ((const float*)p)[i];
}
__device__ __forceinline__ unsigned short f2b_bits(float v) {
    bf16 h = __float2bfloat16(v);
    return *reinterpret_cast<unsigned short*>(&h);
}
__device__ __forceinline__ unsigned short w_bits(const void* p, size_t i, bool bf) {
    if (bf) return ((const unsigned short*)p)[i];
    return f2b_bits(((const float*)p)[i]);
}
__device__ __forceinline__ float bl(unsigned u) { return __uint_as_float(u << 16); }
__device__ __forceinline__ float bh(unsigned u) { return __uint_as_float(u & 0xFFFF0000u); }

// ---------- dtype detection (bf16 vs fp32) ----------
__global__ void detect_k(const void* __restrict__ x, int* __restrict__ flag) {
    __shared__ int cnt;
    if (threadIdx.x == 0) cnt = 0;
    __syncthreads();
    const unsigned short* u = (const unsigned short*)x;
    unsigned short b = u[threadIdx.x * 2];
    int e = (b >> 7) & 0xFF;
    if (e >= 0x70 && e <= 0x8F) atomicAdd(&cnt, 1);
    __syncthreads();
    if (threadIdx.x == 0) *flag = (cnt > 128) ? 1 : 0;
}

// ---------- pad/convert x[N,100] -> bf16 [N,128] ----------
__global__ void xpad_k(const void* __restrict__ x, bf16* __restrict__ xp,
                       const int* __restrict__ flag, int total) {
    int i = blockIdx.x * 256 + threadIdx.x;
    if (i >= total) return;
    const bool bf = (*flag != 0);
    int n = i >> 7, k = i & 127;
    float v = (k < 100) ? ldx(x, (size_t)n * 100 + k, bf) : 0.f;
    xp[i] = __float2bfloat16(v);
}

__global__ void zero_i_k(int* __restrict__ p, int n) {
    int i = blockIdx.x * 256 + threadIdx.x;
    if (i < n) p[i] = 0;
}

// ---------- CSR build (by dst) ----------
__global__ void deg_k(const int* __restrict__ dst, int* __restrict__ deg, int E) {
    int e = blockIdx.x * 256 + threadIdx.x;
    if (e < E) atomicAdd(&deg[dst[e]], 1);
}

__global__ void scan1_k(const int* __restrict__ deg, int* __restrict__ rowptr,
                        int* __restrict__ bsum, int N) {
    __shared__ int buf[256];
    int tid = threadIdx.x, i = blockIdx.x * 256 + tid;
    int v = (i < N) ? deg[i] : 0;
    buf[tid] = v;
    __syncthreads();
    for (int off = 1; off < 256; off <<= 1) {
        int t = (tid >= off) ? buf[tid - off] : 0;
        __syncthreads();
        buf[tid] += t;
        __syncthreads();
    }
    if (i < N) rowptr[i] = buf[tid] - v;
    if (tid == 255) bsum[blockIdx.x] = buf[255];
}

__global__ void scan2_k(const int* __restrict__ bsum, int* __restrict__ boff, int nb) {
    __shared__ int buf[256];
    int tid = threadIdx.x;
    int v = (tid < nb) ? bsum[tid] : 0;
    buf[tid] = v;
    __syncthreads();
    for (int off = 1; off < 256; off <<= 1) {
        int t = (tid >= off) ? buf[tid - off] : 0;
        __syncthreads();
        buf[tid] += t;
        __syncthreads();
    }
    if (tid < nb) boff[tid] = buf[tid] - v;
}

__global__ void scan3_k(int* __restrict__ rowptr, const int* __restrict__ boff,
                        int N, int E) {
    int i = blockIdx.x * 256 + threadIdx.x;
    if (i < N) rowptr[i] += boff[blockIdx.x];
    if (i == 0) rowptr[N] = E;
}

__global__ void fill_k(const int* __restrict__ src, const int* __restrict__ dst,
                       const int* __restrict__ rowptr, int* __restrict__ cur,
                       int* __restrict__ col, int E) {
    int e = blockIdx.x * 256 + threadIdx.x;
    if (e >= E) return;
    int d = dst[e];
    int p = atomicAdd(&cur[d], 1);
    col[rowptr[d] + p] = src[e];
}

// ---------- MFMA GEMM + fused el/er epilogue ----------
// Input: bf16 [N,128] (pre-padded). Output fs bf16 [N,S] in HEAD-PADDED
// layout: head h at cols [h*HS, h*HS+HW), pad cols zero. W^T staged in LDS
// at padded positions. mfma_f32_16x16x32_bf16; D: col=lane&15, row=q*4+reg.
// KW = actual weight rows; M = logical out cols (H*HW).
template <int KW, int M, int S, int HS, int HW>
__global__ void __launch_bounds__(256) gemm_k(const bf16* __restrict__ in,
                                              const void* __restrict__ W,
                                              const void* __restrict__ al,
                                              const void* __restrict__ ar,
                                              bf16* __restrict__ fs,
                                              float* __restrict__ el,
                                              float* __restrict__ er,
                                              const int* __restrict__ flag, int N) {
    constexpr int CT  = S / 16;
    constexpr int WST = 136;
    __shared__ short wlds[S * WST];
    const bool bf = (*flag != 0);
    const int tid = threadIdx.x;

    // ---- stage W^T into LDS at padded cols; zero pad k>=KW, j>=HW ----
    for (int idx = tid; idx < 64 * S; idx += 256) {
        int k2 = idx / S, p = idx % S;
        int j = p % HS, h = p / HS;
        int c = h * HW + j;
        bool valid = (j < HW);
        int k0 = 2 * k2;
        unsigned short u0 = (valid && k0 < KW)     ? w_bits(W, (size_t)k0 * M + c, bf)       : 0;
        unsigned short u1 = (valid && k0 + 1 < KW) ? w_bits(W, (size_t)(k0 + 1) * M + c, bf) : 0;
        *(unsigned*)&wlds[p * WST + 2 * k2] = (unsigned)u0 | ((unsigned)u1 << 16);
    }
    __syncthreads();

    const int wave = tid >> 6, lane = tid & 63;
    const int q = lane >> 4, l16 = lane & 15;
    const int tile_base = blockIdx.x * 64 + wave * 16;
    const int node_a = tile_base + l16;

    floatx4 acc[CT] = {};

#pragma unroll
    for (int chunk = 0; chunk < 4; ++chunk) {
        const int kb = chunk * 32 + q * 8;
        short8 a = {};
        if (node_a < N) a = *(const short8*)(in + (size_t)node_a * 128 + kb);
#pragma unroll
        for (int ct = 0; ct < CT; ++ct) {
            const int p = ct * 16 + l16;
            short8 b = *(const short8*)&wlds[p * WST + kb];
            acc[ct] = __builtin_amdgcn_mfma_f32_16x16x32_bf16(a, b, acc[ct], 0, 0, 0);
        }
    }

    // ---- store fs (padded layout; pad cols hold 0 from zeroed W) ----
#pragma unroll
    for (int ct = 0; ct < CT; ++ct) {
        const int p = ct * 16 + l16;
#pragma unroll
        for (int r = 0; r < 4; ++r) {
            int node = tile_base + q * 4 + r;
            if (node < N) fs[(size_t)node * S + p] = __float2bfloat16(acc[ct][r]);
        }
    }

    // ---- fused el/er from fp32 accumulators (LDS reduce, reuse wlds) ----
    __syncthreads();
    float* red = (float*)wlds;          // 512 slots x 16 floats = 32 KB
    float elp[4][4] = {}, erp[4][4] = {};
#pragma unroll
    for (int ct = 0; ct < CT; ++ct) {
        const int p = ct * 16 + l16;
        const int j = p % HS, h = p / HS;
        const bool valid = (j < HW);
        float alc = valid ? ldx(al, h * HW + j, bf) : 0.f;
        float arc = valid ? ldx(ar, h * HW + j, bf) : 0.f;
#pragma unroll
        for (int r = 0; r < 4; ++r) {
            float v = acc[ct][r];
#pragma unroll
            for (int h2 = 0; h2 < 4; ++h2) {
                elp[r][h2] += (h == h2) ? v * alc : 0.f;
                erp[r][h2] += (h == h2) ? v * arc : 0.f;
            }
        }
    }
#pragma unroll
    for (int r = 0; r < 4; ++r)
#pragma unroll
        for (int h2 = 0; h2 < 4; ++h2) {
            int slot = (wave * 128) + (q * 32) + (r * 8) + (h2 * 2);
            red[slot * 16 + l16] = elp[r][h2];
            red[(slot + 1) * 16 + l16] = erp[r][h2];
        }
    __syncthreads();
#pragma unroll
    for (int pass = 0; pass < 2; ++pass) {
        int slot = tid + pass * 256;
        float sum = 0.f;
#pragma unroll
        for (int j = 0; j < 16; ++j) sum += red[slot * 16 + j];
        int which = slot & 1;
        int h2 = (slot >> 1) & 3;
        int r  = (slot >> 3) & 3;
        int qq = (slot >> 5) & 3;
        int wv = slot >> 7;
        int node = blockIdx.x * 64 + wv * 16 + qq * 4 + r;
        if (node < N) {
            if (which == 0) el[(size_t)node * 4 + h2] = sum;
            else            er[(size_t)node * 4 + h2] = sum;
        }
    }
}

// ---------- agg layers 0/1: staged weights + barrier-free gather, bf16 out --
// One block per dst. HS-strided heads; 8-col lane groups are single-head.
template <int HS, int S, int LPG, int TPB, bool RELU>
__global__ void __launch_bounds__(TPB) agg_k(const float* __restrict__ el,
                                             const float* __restrict__ er,
                                             const bf16* __restrict__ fs,
                                             const int* __restrict__ rowptr,
                                             const int* __restrict__ col,
                                             bf16* __restrict__ out) {
    constexpr int NG = TPB / LPG;
    constexpr int CH = TPB / 4;
    constexpr int NW = TPB / 64;
    const int d = blockIdx.x;
    const int tid = threadIdx.x;
    const int rs = rowptr[d], re = rowptr[d + 1];

    __shared__ float wrow[CH][4];
    __shared__ int scol_s[CH];
    __shared__ float part[NG][S];
    __shared__ float red2[NW][4];
    __shared__ float sh_s[4];

    if (re == rs) {
        if (tid < S / 4) *(uint2*)(out + (size_t)d * S + tid * 4) = make_uint2(0, 0);
        return;
    }

    float4 er4 = *(const float4*)(er + (size_t)d * 4);
    float er_d[4] = {er4.x, er4.y, er4.z, er4.w};

    const int g  = tid / LPG;
    const int lg = tid % LPG;
    const int c0 = lg * 8;
    const int h0 = c0 / HS;             // single head per 8-col group

    float acc[8] = {0, 0, 0, 0, 0, 0, 0, 0};
    float swpart = 0.f;

    for (int cs = rs; cs < re; cs += CH) {
        int ne = min(CH, re - cs);
        if (tid < ne * 4) {
            int j = tid >> 2, h = tid & 3;
            int s = col[cs + j];
            if (h == 0) scol_s[j] = s;
            float x = el[(size_t)s * 4 + h] + er_d[h];
            x = x >= 0.f ? x : 0.2f * x;
            float w = __expf(x);
            wrow[j][h] = w;
            swpart += w;
        }
        __syncthreads();
#pragma unroll 4
        for (int e = g; e < ne; e += NG) {
            int s = scol_s[e];
            uint4 u = *(const uint4*)(fs + (size_t)s * S + c0);
            float w = wrow[e][h0];
            acc[0] += w * bl(u.x); acc[1] += w * bh(u.x);
            acc[2] += w * bl(u.y); acc[3] += w * bh(u.y);
            acc[4] += w * bl(u.z); acc[5] += w * bh(u.z);
            acc[6] += w * bl(u.w); acc[7] += w * bh(u.w);
        }
        __syncthreads();
    }

    float sw = swpart;
#pragma unroll
    for (int off = 4; off < 64; off <<= 1) sw += __shfl_xor(sw, off);
    const int wave = tid >> 6, lane = tid & 63;
    if (lane < 4) red2[wave][lane] = sw;
#pragma unroll
    for (int k = 0; k < 8; ++k) part[g][c0 + k] = acc[k];
    __syncthreads();
    if (tid < 4) {
        float s = 0.f;
#pragma unroll
        for (int w = 0; w < NW; ++w) s += red2[w][tid];
        sh_s[tid] = s;
    }
    __syncthreads();

    if (tid < S / 4) {
        int c = tid * 4;
        float4 v = make_float4(0, 0, 0, 0);
#pragma unroll
        for (int gg = 0; gg < NG; ++gg) {
            v.x += part[gg][c + 0]; v.y += part[gg][c + 1];
            v.z += part[gg][c + 2]; v.w += part[gg][c + 3];
        }
        float is = 1.0f / sh_s[c / HS];
        v.x *= is; v.y *= is; v.z *= is; v.w *= is;
        if (RELU) {
            v.x = fmaxf(v.x, 0.f); v.y = fmaxf(v.y, 0.f);
            v.z = fmaxf(v.z, 0.f); v.w = fmaxf(v.w, 0.f);
        }
        unsigned p0 = (unsigned)f2b_bits(v.x) | ((unsigned)f2b_bits(v.y) << 16);
        unsigned p1 = (unsigned)f2b_bits(v.z) | ((unsigned)f2b_bits(v.w) << 16);
        *(uint2*)(out + (size_t)d * S + c) = make_uint2(p0, p1);
    }
}

// ---------- layer-2 agg + fused head-mean + log_softmax -> d_out ----------
// S=192 head-padded (stride 48, 47 valid). TPB=192, LPG=24, NG=8, CH=48.
__global__ void __launch_bounds__(192) agg2_k(const float* __restrict__ el,
                                              const float* __restrict__ er,
                                              const bf16* __restrict__ fs,
                                              const int* __restrict__ rowptr,
                                              const int* __restrict__ col,
                                              void* __restrict__ out,
                                              const int* __restrict__ flag) {
    constexpr int HS = 48, S = 192, LPG = 24, TPB = 192;
    constexpr int NG = TPB / LPG;       // 8
    constexpr int CH = TPB / 4;         // 48
    constexpr int NW = TPB / 64;        // 3
    const int d = blockIdx.x;
    const int tid = threadIdx.x;
    const bool bf = (*flag != 0);
    const int rs = rowptr[d], re = rowptr[d + 1];

    __shared__ float wrow[CH][4];
    __shared__ int scol_s[CH];
    __shared__ float part[NG][S];
    __shared__ float red2[NW][4];
    __shared__ float sh_s[4];
    __shared__ float vout[S];

    if (re == rs) {                     // isolated: mean=0 -> uniform logits
        if (tid < 47) {
            float r = -logf(47.f);
            if (bf) ((bf16*)out)[(size_t)d * 47 + tid] = __float2bfloat16(r);
            else    ((float*)out)[(size_t)d * 47 + tid] = r;
        }
        return;
    }

    float4 er4 = *(const float4*)(er + (size_t)d * 4);
    float er_d[4] = {er4.x, er4.y, er4.z, er4.w};

    const int g  = tid / LPG;
    const int lg = tid % LPG;
    const int c0 = lg * 8;
    const int h0 = c0 / HS;

    float acc[8] = {0, 0, 0, 0, 0, 0, 0, 0};
    float swpart = 0.f;

    for (int cs = rs; cs < re; cs += CH) {
        int ne = min(CH, re - cs);
        if (tid < ne * 4) {
            int j = tid >> 2, h = tid & 3;
            int s = col[cs + j];
            if (h == 0) scol_s[j] = s;
            float x = el[(size_t)s * 4 + h] + er_d[h];
            x = x >= 0.f ? x : 0.2f * x;
            float w = __expf(x);
            wrow[j][h] = w;
            swpart += w;
        }
        __syncthreads();
#pragma unroll 4
        for (int e = g; e < ne; e += NG) {
            int s = scol_s[e];
            uint4 u = *(const uint4*)(fs + (size_t)s * S + c0);
            float w = wrow[e][h0];
            acc[0] += w * bl(u.x); acc[1] += w * bh(u.x);
            acc[2] += w * bl(u.y); acc[3] += w * bh(u.y);
            acc[4] += w * bl(u.z); acc[5] += w * bh(u.z);
            acc[6] += w * bl(u.w); acc[7] += w * bh(u.w);
        }
        __syncthreads();
    }

    float sw = swpart;
#pragma unroll
    for (int off = 4; off < 64; off <<= 1) sw += __shfl_xor(sw, off);
    const int wave = tid >> 6, lane = tid & 63;
    if (lane < 4) red2[wave][lane] = sw;
#pragma unroll
    for (int k = 0; k < 8; ++k) part[g][c0 + k] = acc[k];
    __syncthreads();
    if (tid < 4) {
        float s = 0.f;
#pragma unroll
        for (int w = 0; w < NW; ++w) s += red2[w][tid];
        sh_s[tid] = s;
    }
    __syncthreads();

    if (tid < S / 4) {
        int c = tid * 4;
        float4 v = make_float4(0, 0, 0, 0);
#pragma unroll
        for (int gg = 0; gg < NG; ++gg) {
            v.x += part[gg][c + 0]; v.y += part[gg][c + 1];
            v.z += part[gg][c + 2]; v.w += part[gg][c + 3];
        }
        float is = 1.0f / sh_s[c / HS];
        vout[c + 0] = v.x * is; vout[c + 1] = v.y * is;
        vout[c + 2] = v.z * is; vout[c + 3] = v.w * is;
    }
    __syncthreads();

    // wave 0: head-mean over padded heads + log_softmax over 47 classes
    if (tid < 64) {
        int c = tid;
        float val = 0.f, vm = -INFINITY;
        if (c < 47) {
            val = 0.25f * (vout[c] + vout[48 + c] + vout[96 + c] + vout[144 + c]);
            vm = val;
        }
        float m = vm;
#pragma unroll
        for (int off = 32; off >= 1; off >>= 1) m = fmaxf(m, __shfl_xor(m, off));
        float ex = (c < 47) ? __expf(val - m) : 0.f;
        float s = ex;
#pragma unroll
        for (int off = 32; off >= 1; off >>= 1) s += __shfl_xor(s, off);
        if (c < 47) {
            float r = val - m - logf(s);
            if (bf) ((bf16*)out)[(size_t)d * 47 + c] = __float2bfloat16(r);
            else    ((float*)out)[(size_t)d * 47 + c] = r;
        }
    }
}

extern "C" void kernel_launch(void* const* d_in, const int* in_sizes, int n_in,
                              void* d_out, int out_size, void* d_ws, size_t ws_size,
                              hipStream_t stream) {
    const void* x   = d_in[0];
    const void* W0  = d_in[1];
    const void* al0 = d_in[2];
    const void* ar0 = d_in[3];
    const void* W1  = d_in[4];
    const void* al1 = d_in[5];
    const void* ar1 = d_in[6];
    const void* W2  = d_in[7];
    const void* al2 = d_in[8];
    const void* ar2 = d_in[9];
    const int* src  = (const int*)d_in[10];
    const int* dst  = (const int*)d_in[11];
    const int E = in_sizes[10];
    const int N = NN;

    bf16* fs    = (bf16*)d_ws;                    // N*192 bf16
    bf16* hb16  = fs + (size_t)N * 192;           // N*128 bf16
    bf16* xpad  = hb16 + (size_t)N * 128;         // N*128 bf16
    float* el   = (float*)(xpad + (size_t)N * 128); // N*4
    float* er   = el + (size_t)N * H;             // N*4
    int* rowptr = (int*)(er + (size_t)N * H);     // N+1
    int* cur    = rowptr + (N + 1);               // N
    int* col    = cur + N;                        // E
    int* bsum   = col + E;                        // 256
    int* boff   = bsum + 256;                     // 256
    int* flag   = boff + 256;                     // 1

    const int gN = (N + 255) / 256;               // 196 blocks
    const int gE = (E + 255) / 256;
    const int gG = (N + 63) / 64;                 // 782 gemm blocks

    detect_k<<<1, 256, 0, stream>>>(x, flag);
    xpad_k<<<(N * 128 + 255) / 256, 256, 0, stream>>>(x, xpad, flag, N * 128);

    // CSR build (graph identical for all 3 layers)
    zero_i_k<<<gN, 256, 0, stream>>>(cur, N);
    deg_k<<<gE, 256, 0, stream>>>(dst, cur, E);
    scan1_k<<<gN, 256, 0, stream>>>(cur, rowptr, bsum, N);
    scan2_k<<<1, 256, 0, stream>>>(bsum, boff, gN);
    scan3_k<<<gN, 256, 0, stream>>>(rowptr, boff, N, E);
    zero_i_k<<<gN, 256, 0, stream>>>(cur, N);
    fill_k<<<gE, 256, 0, stream>>>(src, dst, rowptr, cur, col, E);

    // ---------------- Layer 0: W[100,128], HS=HW=32 ----------------
    gemm_k<100, 128, 128, 32, 32><<<gG, 256, 0, stream>>>(
        xpad, W0, al0, ar0, fs, el, er, flag, N);
    agg_k<32, 128, 16, 256, true><<<N, 256, 0, stream>>>(el, er, fs, rowptr, col, hb16);

    // ---------------- Layer 1: W[128,128], HS=HW=32 ----------------
    gemm_k<128, 128, 128, 32, 32><<<gG, 256, 0, stream>>>(
        hb16, W1, al1, ar1, fs, el, er, flag, N);
    agg_k<32, 128, 16, 256, true><<<N, 256, 0, stream>>>(el, er, fs, rowptr, col, hb16);

    // ---------------- Layer 2: W[128,188], HS=48, HW=47 (head-padded) ------
    gemm_k<128, 188, 192, 48, 47><<<gG, 256, 0, stream>>>(
        hb16, W2, al2, ar2, fs, el, er, flag, N);
    agg2_k<<<N, 192, 0, stream>>>(el, er, fs, rowptr, col, d_out, flag);
}

// Round 11
// 598.283 us; speedup vs baseline: 1.0774x; 1.0774x over previous
//
#include <hip/hip_runtime.h>
#include <hip/hip_bf16.h>

// GAT 3-layer forward. N=50000, E=1.6M, H=4, D=32, C=47.
// Round 11: wave-autonomous agg for layers 0/1 (1 wave = 1 dst, ZERO
// barriers, shfl reduce), gemm processes 128 nodes/block (halves W staging),
// memsetAsync for zeroing. Layer-2 agg (memory-bound at gather ceiling)
// unchanged from R10.
//
// ws: fs[N*192 bf16] hb16[N*128 bf16] xpad[N*128 bf16] el/er[N*4 f32]
//     rowptr cur col flag  => ~53 MB.

using bf16 = __hip_bfloat16;
typedef __attribute__((ext_vector_type(8))) short short8;
typedef __attribute__((ext_vector_type(4))) float floatx4;

static constexpr int NN = 50000;
static constexpr int H  = 4;

__device__ __forceinline__ float b2f(bf16 x) { return __bfloat162float(x); }
__device__ __forceinline__ float ldx(const void* p, size_t i, bool bf) {
    return bf ? __bfloat162float(((const bf16*)p)[i]) : ((const float*)p)[i];
}
__device__ __forceinline__ unsigned short f2b_bits(float v) {
    bf16 h = __float2bfloat16(v);
    return *reinterpret_cast<unsigned short*>(&h);
}
__device__ __forceinline__ unsigned short w_bits(const void* p, size_t i, bool bf) {
    if (bf) return ((const unsigned short*)p)[i];
    return f2b_bits(((const float*)p)[i]);
}
__device__ __forceinline__ float bl(unsigned u) { return __uint_as_float(u << 16); }
__device__ __forceinline__ float bh(unsigned u) { return __uint_as_float(u & 0xFFFF0000u); }

// ---------- dtype detection (bf16 vs fp32) ----------
__global__ void detect_k(const void* __restrict__ x, int* __restrict__ flag) {
    __shared__ int cnt;
    if (threadIdx.x == 0) cnt = 0;
    __syncthreads();
    const unsigned short* u = (const unsigned short*)x;
    unsigned short b = u[threadIdx.x * 2];
    int e = (b >> 7) & 0xFF;
    if (e >= 0x70 && e <= 0x8F) atomicAdd(&cnt, 1);
    __syncthreads();
    if (threadIdx.x == 0) *flag = (cnt > 128) ? 1 : 0;
}

// ---------- pad/convert x[N,100] -> bf16 [N,128] ----------
__global__ void xpad_k(const void* __restrict__ x, bf16* __restrict__ xp,
                       const int* __restrict__ flag, int total) {
    int i = blockIdx.x * 256 + threadIdx.x;
    if (i >= total) return;
    const bool bf = (*flag != 0);
    int n = i >> 7, k = i & 127;
    float v = (k < 100) ? ldx(x, (size_t)n * 100 + k, bf) : 0.f;
    xp[i] = __float2bfloat16(v);
}

// ---------- CSR build (by dst) ----------
__global__ void deg_k(const int* __restrict__ dst, int* __restrict__ deg, int E) {
    int e = blockIdx.x * 256 + threadIdx.x;
    if (e < E) atomicAdd(&deg[dst[e]], 1);
}

__global__ void scan1_k(const int* __restrict__ deg, int* __restrict__ rowptr,
                        int* __restrict__ bsum, int N) {
    __shared__ int buf[256];
    int tid = threadIdx.x, i = blockIdx.x * 256 + tid;
    int v = (i < N) ? deg[i] : 0;
    buf[tid] = v;
    __syncthreads();
    for (int off = 1; off < 256; off <<= 1) {
        int t = (tid >= off) ? buf[tid - off] : 0;
        __syncthreads();
        buf[tid] += t;
        __syncthreads();
    }
    if (i < N) rowptr[i] = buf[tid] - v;
    if (tid == 255) bsum[blockIdx.x] = buf[255];
}

__global__ void scan2_k(const int* __restrict__ bsum, int* __restrict__ boff, int nb) {
    __shared__ int buf[256];
    int tid = threadIdx.x;
    int v = (tid < nb) ? bsum[tid] : 0;
    buf[tid] = v;
    __syncthreads();
    for (int off = 1; off < 256; off <<= 1) {
        int t = (tid >= off) ? buf[tid - off] : 0;
        __syncthreads();
        buf[tid] += t;
        __syncthreads();
    }
    if (tid < nb) boff[tid] = buf[tid] - v;
}

__global__ void scan3_k(int* __restrict__ rowptr, const int* __restrict__ boff,
                        int N, int E) {
    int i = blockIdx.x * 256 + threadIdx.x;
    if (i < N) rowptr[i] += boff[blockIdx.x];
    if (i == 0) rowptr[N] = E;
}

__global__ void fill_k(const int* __restrict__ src, const int* __restrict__ dst,
                       const int* __restrict__ rowptr, int* __restrict__ cur,
                       int* __restrict__ col, int E) {
    int e = blockIdx.x * 256 + threadIdx.x;
    if (e >= E) return;
    int d = dst[e];
    int p = atomicAdd(&cur[d], 1);
    col[rowptr[d] + p] = src[e];
}

// ---------- MFMA GEMM (128 nodes/block) + fused el/er epilogue ----------
// Input: bf16 [N,128]. Output fs bf16 [N,S] head-padded (head h at cols
// [h*HS, h*HS+HW)). W^T in LDS (stride 136 shorts); each wave does 2 row
// tiles (nodes base+w*16 and +64), B-frag LDS read shared across both.
template <int KW, int M, int S, int HS, int HW>
__global__ void __launch_bounds__(256) gemm_k(const bf16* __restrict__ in,
                                              const void* __restrict__ W,
                                              const void* __restrict__ al,
                                              const void* __restrict__ ar,
                                              bf16* __restrict__ fs,
                                              float* __restrict__ el,
                                              float* __restrict__ er,
                                              const int* __restrict__ flag, int N) {
    constexpr int CT  = S / 16;
    constexpr int WST = 136;
    __shared__ short wlds[S * WST];
    const bool bf = (*flag != 0);
    const int tid = threadIdx.x;

    // ---- stage W^T into LDS at padded cols; zero pad k>=KW, j>=HW ----
    for (int idx = tid; idx < 64 * S; idx += 256) {
        int k2 = idx / S, p = idx % S;
        int j = p % HS, h = p / HS;
        int c = h * HW + j;
        bool valid = (j < HW);
        int k0 = 2 * k2;
        unsigned short u0 = (valid && k0 < KW)     ? w_bits(W, (size_t)k0 * M + c, bf)       : 0;
        unsigned short u1 = (valid && k0 + 1 < KW) ? w_bits(W, (size_t)(k0 + 1) * M + c, bf) : 0;
        *(unsigned*)&wlds[p * WST + 2 * k2] = (unsigned)u0 | ((unsigned)u1 << 16);
    }
    __syncthreads();

    const int wave = tid >> 6, lane = tid & 63;
    const int q = lane >> 4, l16 = lane & 15;
    const int base = blockIdx.x * 128;

    floatx4 acc[2][CT] = {};

#pragma unroll
    for (int chunk = 0; chunk < 4; ++chunk) {
        const int kb = chunk * 32 + q * 8;
        short8 a0 = {}, a1 = {};
        const int n0 = base + wave * 16 + l16;
        const int n1 = n0 + 64;
        if (n0 < N) a0 = *(const short8*)(in + (size_t)n0 * 128 + kb);
        if (n1 < N) a1 = *(const short8*)(in + (size_t)n1 * 128 + kb);
#pragma unroll
        for (int ct = 0; ct < CT; ++ct) {
            const int p = ct * 16 + l16;
            short8 b = *(const short8*)&wlds[p * WST + kb];
            acc[0][ct] = __builtin_amdgcn_mfma_f32_16x16x32_bf16(a0, b, acc[0][ct], 0, 0, 0);
            acc[1][ct] = __builtin_amdgcn_mfma_f32_16x16x32_bf16(a1, b, acc[1][ct], 0, 0, 0);
        }
    }

    // ---- store fs (both row tiles) ----
#pragma unroll
    for (int rt = 0; rt < 2; ++rt) {
        const int tb = base + rt * 64 + wave * 16;
#pragma unroll
        for (int ct = 0; ct < CT; ++ct) {
            const int p = ct * 16 + l16;
#pragma unroll
            for (int r = 0; r < 4; ++r) {
                int node = tb + q * 4 + r;
                if (node < N) fs[(size_t)node * S + p] = __float2bfloat16(acc[rt][ct][r]);
            }
        }
    }

    // ---- fused el/er from fp32 accumulators (two passes, reuse wlds) ----
    float* red = (float*)wlds;          // 512 slots x 16 floats = 32 KB
#pragma unroll
    for (int rt = 0; rt < 2; ++rt) {
        __syncthreads();                // previous reads of red/wlds done
        float elp[4][4] = {}, erp[4][4] = {};
#pragma unroll
        for (int ct = 0; ct < CT; ++ct) {
            const int p = ct * 16 + l16;
            const int j = p % HS, h = p / HS;
            const bool valid = (j < HW);
            float alc = valid ? ldx(al, h * HW + j, bf) : 0.f;
            float arc = valid ? ldx(ar, h * HW + j, bf) : 0.f;
#pragma unroll
            for (int r = 0; r < 4; ++r) {
                float v = acc[rt][ct][r];
#pragma unroll
                for (int h2 = 0; h2 < 4; ++h2) {
                    elp[r][h2] += (h == h2) ? v * alc : 0.f;
                    erp[r][h2] += (h == h2) ? v * arc : 0.f;
                }
            }
        }
#pragma unroll
        for (int r = 0; r < 4; ++r)
#pragma unroll
            for (int h2 = 0; h2 < 4; ++h2) {
                int slot = (wave * 128) + (q * 32) + (r * 8) + (h2 * 2);
                red[slot * 16 + l16] = elp[r][h2];
                red[(slot + 1) * 16 + l16] = erp[r][h2];
            }
        __syncthreads();
#pragma unroll
        for (int pass = 0; pass < 2; ++pass) {
            int slot = tid + pass * 256;
            float sum = 0.f;
#pragma unroll
            for (int j = 0; j < 16; ++j) sum += red[slot * 16 + j];
            int which = slot & 1;
            int h2 = (slot >> 1) & 3;
            int r  = (slot >> 3) & 3;
            int qq = (slot >> 5) & 3;
            int wv = slot >> 7;
            int node = base + rt * 64 + wv * 16 + qq * 4 + r;
            if (node < N) {
                if (which == 0) el[(size_t)node * 4 + h2] = sum;
                else            er[(size_t)node * 4 + h2] = sum;
            }
        }
    }
}

// ---------- wave-autonomous agg, layers 0/1 (S=128, HS=32) ----------
// One wave per dst node, 4 dst/block. Staging: lane (e=lane>>2, h=lane&3)
// computes weight for up to 16 edges/chunk into wave-private LDS; gather:
// 4 groups x 16 lanes x 16B. Same-wave LDS producer/consumer -> NO barriers.
// Cross-group reduce via shfl_xor(16,32); weight sums via butterfly.
template <bool RELU>
__global__ void __launch_bounds__(256) agg01_k(const float* __restrict__ el,
                                               const float* __restrict__ er,
                                               const bf16* __restrict__ fs,
                                               const int* __restrict__ rowptr,
                                               const int* __restrict__ col,
                                               bf16* __restrict__ out, int N) {
    const int wave = threadIdx.x >> 6, lane = threadIdx.x & 63;
    const int d = blockIdx.x * 4 + wave;
    __shared__ float wrow[4][16][4];
    __shared__ int   scol[4][16];
    if (d >= N) return;
    const int rs = rowptr[d], re = rowptr[d + 1];
    const int g = lane >> 4, lg = lane & 15;
    const int c0 = lg * 8;                  // 8 bf16 cols = 16 B per lane

    if (re == rs) {                         // isolated -> zero row
        if (g == 0) *(uint4*)(out + (size_t)d * 128 + c0) = make_uint4(0, 0, 0, 0);
        return;
    }

    float4 er4 = *(const float4*)(er + (size_t)d * 4);
    float er_d[4] = {er4.x, er4.y, er4.z, er4.w};

    const int eh = lane >> 2;               // staged edge (0..15)
    const int hh = lane & 3;                // staged head
    const int h0 = lg >> 2;                 // gather head (c0/32)

    float acc[8] = {0, 0, 0, 0, 0, 0, 0, 0};
    float swp = 0.f;

    for (int cs = rs; cs < re; cs += 16) {
        int ne = min(16, re - cs);
        if (eh < ne) {
            int s = col[cs + eh];
            if (hh == 0) scol[wave][eh] = s;
            float x = el[(size_t)s * 4 + hh] + er_d[hh];
            x = x >= 0.f ? x : 0.2f * x;
            float w = __expf(x);
            wrow[wave][eh][hh] = w;
            swp += w;
        }
        // same-wave LDS dependency: compiler inserts lgkmcnt, no barrier
#pragma unroll 4
        for (int e = g; e < ne; e += 4) {
            int s = scol[wave][e];
            float w = wrow[wave][e][h0];
            uint4 u = *(const uint4*)(fs + (size_t)s * 128 + c0);
            acc[0] += w * bl(u.x); acc[1] += w * bh(u.x);
            acc[2] += w * bl(u.y); acc[3] += w * bh(u.y);
            acc[4] += w * bl(u.z); acc[5] += w * bh(u.z);
            acc[6] += w * bl(u.w); acc[7] += w * bh(u.w);
        }
    }

    // cross-group reduce (groups differ in lane bits 4,5)
#pragma unroll
    for (int k = 0; k < 8; ++k) {
        acc[k] += __shfl_xor(acc[k], 16);
        acc[k] += __shfl_xor(acc[k], 32);
    }
    // per-head weight sums: butterfly over lane bits 2..5 keeps lane&3 class
#pragma unroll
    for (int off = 4; off < 64; off <<= 1) swp += __shfl_xor(swp, off);
    float sh = __shfl(swp, h0);             // lane h0 holds head-h0 total

    if (g == 0) {
        float inv = 1.0f / sh;
        float v[8];
#pragma unroll
        for (int k = 0; k < 8; ++k) {
            v[k] = acc[k] * inv;
            if (RELU) v[k] = fmaxf(v[k], 0.f);
        }
        uint4 o;
        o.x = (unsigned)f2b_bits(v[0]) | ((unsigned)f2b_bits(v[1]) << 16);
        o.y = (unsigned)f2b_bits(v[2]) | ((unsigned)f2b_bits(v[3]) << 16);
        o.z = (unsigned)f2b_bits(v[4]) | ((unsigned)f2b_bits(v[5]) << 16);
        o.w = (unsigned)f2b_bits(v[6]) | ((unsigned)f2b_bits(v[7]) << 16);
        *(uint4*)(out + (size_t)d * 128 + c0) = o;
    }
}

// ---------- layer-2 agg + fused head-mean + log_softmax -> d_out ----------
// S=192 head-padded (stride 48, 47 valid). TPB=192, LPG=24, NG=8, CH=48.
__global__ void __launch_bounds__(192) agg2_k(const float* __restrict__ el,
                                              const float* __restrict__ er,
                                              const bf16* __restrict__ fs,
                                              const int* __restrict__ rowptr,
                                              const int* __restrict__ col,
                                              void* __restrict__ out,
                                              const int* __restrict__ flag) {
    constexpr int HS = 48, S = 192, LPG = 24, TPB = 192;
    constexpr int NG = TPB / LPG;       // 8
    constexpr int CH = TPB / 4;         // 48
    constexpr int NW = TPB / 64;        // 3
    const int d = blockIdx.x;
    const int tid = threadIdx.x;
    const bool bf = (*flag != 0);
    const int rs = rowptr[d], re = rowptr[d + 1];

    __shared__ float wrow[CH][4];
    __shared__ int scol_s[CH];
    __shared__ float part[NG][S];
    __shared__ float red2[NW][4];
    __shared__ float sh_s[4];
    __shared__ float vout[S];

    if (re == rs) {                     // isolated: mean=0 -> uniform logits
        if (tid < 47) {
            float r = -logf(47.f);
            if (bf) ((bf16*)out)[(size_t)d * 47 + tid] = __float2bfloat16(r);
            else    ((float*)out)[(size_t)d * 47 + tid] = r;
        }
        return;
    }

    float4 er4 = *(const float4*)(er + (size_t)d * 4);
    float er_d[4] = {er4.x, er4.y, er4.z, er4.w};

    const int g  = tid / LPG;
    const int lg = tid % LPG;
    const int c0 = lg * 8;
    const int h0 = c0 / HS;

    float acc[8] = {0, 0, 0, 0, 0, 0, 0, 0};
    float swpart = 0.f;

    for (int cs = rs; cs < re; cs += CH) {
        int ne = min(CH, re - cs);
        if (tid < ne * 4) {
            int j = tid >> 2, h = tid & 3;
            int s = col[cs + j];
            if (h == 0) scol_s[j] = s;
            float x = el[(size_t)s * 4 + h] + er_d[h];
            x = x >= 0.f ? x : 0.2f * x;
            float w = __expf(x);
            wrow[j][h] = w;
            swpart += w;
        }
        __syncthreads();
#pragma unroll 4
        for (int e = g; e < ne; e += NG) {
            int s = scol_s[e];
            uint4 u = *(const uint4*)(fs + (size_t)s * S + c0);
            float w = wrow[e][h0];
            acc[0] += w * bl(u.x); acc[1] += w * bh(u.x);
            acc[2] += w * bl(u.y); acc[3] += w * bh(u.y);
            acc[4] += w * bl(u.z); acc[5] += w * bh(u.z);
            acc[6] += w * bl(u.w); acc[7] += w * bh(u.w);
        }
        __syncthreads();
    }

    float sw = swpart;
#pragma unroll
    for (int off = 4; off < 64; off <<= 1) sw += __shfl_xor(sw, off);
    const int wave = tid >> 6, lane = tid & 63;
    if (lane < 4) red2[wave][lane] = sw;
#pragma unroll
    for (int k = 0; k < 8; ++k) part[g][c0 + k] = acc[k];
    __syncthreads();
    if (tid < 4) {
        float s = 0.f;
#pragma unroll
        for (int w = 0; w < NW; ++w) s += red2[w][tid];
        sh_s[tid] = s;
    }
    __syncthreads();

    if (tid < S / 4) {
        int c = tid * 4;
        float4 v = make_float4(0, 0, 0, 0);
#pragma unroll
        for (int gg = 0; gg < NG; ++gg) {
            v.x += part[gg][c + 0]; v.y += part[gg][c + 1];
            v.z += part[gg][c + 2]; v.w += part[gg][c + 3];
        }
        float is = 1.0f / sh_s[c / HS];
        vout[c + 0] = v.x * is; vout[c + 1] = v.y * is;
        vout[c + 2] = v.z * is; vout[c + 3] = v.w * is;
    }
    __syncthreads();

    if (tid < 64) {
        int c = tid;
        float val = 0.f, vm = -INFINITY;
        if (c < 47) {
            val = 0.25f * (vout[c] + vout[48 + c] + vout[96 + c] + vout[144 + c]);
            vm = val;
        }
        float m = vm;
#pragma unroll
        for (int off = 32; off >= 1; off >>= 1) m = fmaxf(m, __shfl_xor(m, off));
        float ex = (c < 47) ? __expf(val - m) : 0.f;
        float s = ex;
#pragma unroll
        for (int off = 32; off >= 1; off >>= 1) s += __shfl_xor(s, off);
        if (c < 47) {
            float r = val - m - logf(s);
            if (bf) ((bf16*)out)[(size_t)d * 47 + c] = __float2bfloat16(r);
            else    ((float*)out)[(size_t)d * 47 + c] = r;
        }
    }
}

extern "C" void kernel_launch(void* const* d_in, const int* in_sizes, int n_in,
                              void* d_out, int out_size, void* d_ws, size_t ws_size,
                              hipStream_t stream) {
    const void* x   = d_in[0];
    const void* W0  = d_in[1];
    const void* al0 = d_in[2];
    const void* ar0 = d_in[3];
    const void* W1  = d_in[4];
    const void* al1 = d_in[5];
    const void* ar1 = d_in[6];
    const void* W2  = d_in[7];
    const void* al2 = d_in[8];
    const void* ar2 = d_in[9];
    const int* src  = (const int*)d_in[10];
    const int* dst  = (const int*)d_in[11];
    const int E = in_sizes[10];
    const int N = NN;

    bf16* fs    = (bf16*)d_ws;                      // N*192 bf16
    bf16* hb16  = fs + (size_t)N * 192;             // N*128 bf16
    bf16* xpad  = hb16 + (size_t)N * 128;           // N*128 bf16
    float* el   = (float*)(xpad + (size_t)N * 128); // N*4
    float* er   = el + (size_t)N * H;               // N*4
    int* rowptr = (int*)(er + (size_t)N * H);       // N+1
    int* cur    = rowptr + (N + 1);                 // N
    int* col    = cur + N;                          // E
    int* bsum   = col + E;                          // 256
    int* boff   = bsum + 256;                       // 256
    int* flag   = boff + 256;                       // 1

    const int gN  = (N + 255) / 256;                // 196 blocks
    const int gE  = (E + 255) / 256;
    const int gG  = (N + 127) / 128;                // 391 gemm blocks
    const int gA  = (N + 3) / 4;                    // 12500 agg01 blocks

    detect_k<<<1, 256, 0, stream>>>(x, flag);
    xpad_k<<<(N * 128 + 255) / 256, 256, 0, stream>>>(x, xpad, flag, N * 128);

    // CSR build (graph identical for all 3 layers)
    hipMemsetAsync(cur, 0, (size_t)N * 4, stream);
    deg_k<<<gE, 256, 0, stream>>>(dst, cur, E);
    scan1_k<<<gN, 256, 0, stream>>>(cur, rowptr, bsum, N);
    scan2_k<<<1, 256, 0, stream>>>(bsum, boff, gN);
    scan3_k<<<gN, 256, 0, stream>>>(rowptr, boff, N, E);
    hipMemsetAsync(cur, 0, (size_t)N * 4, stream);
    fill_k<<<gE, 256, 0, stream>>>(src, dst, rowptr, cur, col, E);

    // ---------------- Layer 0: W[100,128], HS=HW=32 ----------------
    gemm_k<100, 128, 128, 32, 32><<<gG, 256, 0, stream>>>(
        xpad, W0, al0, ar0, fs, el, er, flag, N);
    agg01_k<true><<<gA, 256, 0, stream>>>(el, er, fs, rowptr, col, hb16, N);

    // ---------------- Layer 1: W[128,128], HS=HW=32 ----------------
    gemm_k<128, 128, 128, 32, 32><<<gG, 256, 0, stream>>>(
        hb16, W1, al1, ar1, fs, el, er, flag, N);
    agg01_k<true><<<gA, 256, 0, stream>>>(el, er, fs, rowptr, col, hb16, N);

    // ---------------- Layer 2: W[128,188], HS=48, HW=47 (head-padded) ------
    gemm_k<128, 188, 192, 48, 47><<<gG, 256, 0, stream>>>(
        hb16, W2, al2, ar2, fs, el, er, flag, N);
    agg2_k<<<N, 192, 0, stream>>>(el, er, fs, rowptr, col, d_out, flag);
}

// Round 12
// 533.764 us; speedup vs baseline: 1.2077x; 1.1209x over previous
//
#include <hip/hip_runtime.h>
#include <hip/hip_bf16.h>

// GAT 3-layer forward. N=50000, E=1.6M, H=4, D=32, C=47.
// Round 12: CSR fill de-amplified -- col stored as ushort (node id < 65536,
// halves the 64B-line writeback amplification measured at 102 MB for a
// 6.4 MB array) and edge slots captured from deg_k's atomicAdd return
// (fill_k has zero atomics, one less memset).
//
// ws: fs[N*192 bf16] hb16[N*128 bf16] xpad[N*128 bf16] el/er[N*4 f32]
//     rowptr[N+1] col16[E u16] slot16[E u16] bsum boff flag  => ~50 MB.

using bf16 = __hip_bfloat16;
typedef __attribute__((ext_vector_type(8))) short short8;
typedef __attribute__((ext_vector_type(4))) float floatx4;

static constexpr int NN = 50000;
static constexpr int H  = 4;

__device__ __forceinline__ float b2f(bf16 x) { return __bfloat162float(x); }
__device__ __forceinline__ float ldx(const void* p, size_t i, bool bf) {
    return bf ? __bfloat162float(((const bf16*)p)[i]) : ((const float*)p)[i];
}
__device__ __forceinline__ unsigned short f2b_bits(float v) {
    bf16 h = __float2bfloat16(v);
    return *reinterpret_cast<unsigned short*>(&h);
}
__device__ __forceinline__ unsigned short w_bits(const void* p, size_t i, bool bf) {
    if (bf) return ((const unsigned short*)p)[i];
    return f2b_bits(((const float*)p)[i]);
}
__device__ __forceinline__ float bl(unsigned u) { return __uint_as_float(u << 16); }
__device__ __forceinline__ float bh(unsigned u) { return __uint_as_float(u & 0xFFFF0000u); }

// ---------- dtype detection (bf16 vs fp32) ----------
__global__ void detect_k(const void* __restrict__ x, int* __restrict__ flag) {
    __shared__ int cnt;
    if (threadIdx.x == 0) cnt = 0;
    __syncthreads();
    const unsigned short* u = (const unsigned short*)x;
    unsigned short b = u[threadIdx.x * 2];
    int e = (b >> 7) & 0xFF;
    if (e >= 0x70 && e <= 0x8F) atomicAdd(&cnt, 1);
    __syncthreads();
    if (threadIdx.x == 0) *flag = (cnt > 128) ? 1 : 0;
}

// ---------- pad/convert x[N,100] -> bf16 [N,128] ----------
__global__ void xpad_k(const void* __restrict__ x, bf16* __restrict__ xp,
                       const int* __restrict__ flag, int total) {
    int i = blockIdx.x * 256 + threadIdx.x;
    if (i >= total) return;
    const bool bf = (*flag != 0);
    int n = i >> 7, k = i & 127;
    float v = (k < 100) ? ldx(x, (size_t)n * 100 + k, bf) : 0.f;
    xp[i] = __float2bfloat16(v);
}

// ---------- CSR build (by dst); deg pass also captures per-edge slot ----------
__global__ void deg_k(const int* __restrict__ dst, int* __restrict__ deg,
                      unsigned short* __restrict__ slot16, int E) {
    int e = blockIdx.x * 256 + threadIdx.x;
    if (e >= E) return;
    int p = atomicAdd(&deg[dst[e]], 1);
    slot16[e] = (unsigned short)p;
}

__global__ void scan1_k(const int* __restrict__ deg, int* __restrict__ rowptr,
                        int* __restrict__ bsum, int N) {
    __shared__ int buf[256];
    int tid = threadIdx.x, i = blockIdx.x * 256 + tid;
    int v = (i < N) ? deg[i] : 0;
    buf[tid] = v;
    __syncthreads();
    for (int off = 1; off < 256; off <<= 1) {
        int t = (tid >= off) ? buf[tid - off] : 0;
        __syncthreads();
        buf[tid] += t;
        __syncthreads();
    }
    if (i < N) rowptr[i] = buf[tid] - v;
    if (tid == 255) bsum[blockIdx.x] = buf[255];
}

__global__ void scan2_k(const int* __restrict__ bsum, int* __restrict__ boff, int nb) {
    __shared__ int buf[256];
    int tid = threadIdx.x;
    int v = (tid < nb) ? bsum[tid] : 0;
    buf[tid] = v;
    __syncthreads();
    for (int off = 1; off < 256; off <<= 1) {
        int t = (tid >= off) ? buf[tid - off] : 0;
        __syncthreads();
        buf[tid] += t;
        __syncthreads();
    }
    if (tid < nb) boff[tid] = buf[tid] - v;
}

__global__ void scan3_k(int* __restrict__ rowptr, const int* __restrict__ boff,
                        int N, int E) {
    int i = blockIdx.x * 256 + threadIdx.x;
    if (i < N) rowptr[i] += boff[blockIdx.x];
    if (i == 0) rowptr[N] = E;
}

// atomic-free fill: slot from deg pass, ushort scatter (half the line churn)
__global__ void fill_k(const int* __restrict__ src, const int* __restrict__ dst,
                       const int* __restrict__ rowptr,
                       const unsigned short* __restrict__ slot16,
                       unsigned short* __restrict__ col16, int E) {
    int e = blockIdx.x * 256 + threadIdx.x;
    if (e >= E) return;
    int d = dst[e];
    col16[rowptr[d] + slot16[e]] = (unsigned short)src[e];
}

// ---------- MFMA GEMM (128 nodes/block) + fused el/er epilogue ----------
template <int KW, int M, int S, int HS, int HW>
__global__ void __launch_bounds__(256) gemm_k(const bf16* __restrict__ in,
                                              const void* __restrict__ W,
                                              const void* __restrict__ al,
                                              const void* __restrict__ ar,
                                              bf16* __restrict__ fs,
                                              float* __restrict__ el,
                                              float* __restrict__ er,
                                              const int* __restrict__ flag, int N) {
    constexpr int CT  = S / 16;
    constexpr int WST = 136;
    __shared__ short wlds[S * WST];
    const bool bf = (*flag != 0);
    const int tid = threadIdx.x;

    for (int idx = tid; idx < 64 * S; idx += 256) {
        int k2 = idx / S, p = idx % S;
        int j = p % HS, h = p / HS;
        int c = h * HW + j;
        bool valid = (j < HW);
        int k0 = 2 * k2;
        unsigned short u0 = (valid && k0 < KW)     ? w_bits(W, (size_t)k0 * M + c, bf)       : 0;
        unsigned short u1 = (valid && k0 + 1 < KW) ? w_bits(W, (size_t)(k0 + 1) * M + c, bf) : 0;
        *(unsigned*)&wlds[p * WST + 2 * k2] = (unsigned)u0 | ((unsigned)u1 << 16);
    }
    __syncthreads();

    const int wave = tid >> 6, lane = tid & 63;
    const int q = lane >> 4, l16 = lane & 15;
    const int base = blockIdx.x * 128;

    floatx4 acc[2][CT] = {};

#pragma unroll
    for (int chunk = 0; chunk < 4; ++chunk) {
        const int kb = chunk * 32 + q * 8;
        short8 a0 = {}, a1 = {};
        const int n0 = base + wave * 16 + l16;
        const int n1 = n0 + 64;
        if (n0 < N) a0 = *(const short8*)(in + (size_t)n0 * 128 + kb);
        if (n1 < N) a1 = *(const short8*)(in + (size_t)n1 * 128 + kb);
#pragma unroll
        for (int ct = 0; ct < CT; ++ct) {
            const int p = ct * 16 + l16;
            short8 b = *(const short8*)&wlds[p * WST + kb];
            acc[0][ct] = __builtin_amdgcn_mfma_f32_16x16x32_bf16(a0, b, acc[0][ct], 0, 0, 0);
            acc[1][ct] = __builtin_amdgcn_mfma_f32_16x16x32_bf16(a1, b, acc[1][ct], 0, 0, 0);
        }
    }

#pragma unroll
    for (int rt = 0; rt < 2; ++rt) {
        const int tb = base + rt * 64 + wave * 16;
#pragma unroll
        for (int ct = 0; ct < CT; ++ct) {
            const int p = ct * 16 + l16;
#pragma unroll
            for (int r = 0; r < 4; ++r) {
                int node = tb + q * 4 + r;
                if (node < N) fs[(size_t)node * S + p] = __float2bfloat16(acc[rt][ct][r]);
            }
        }
    }

    float* red = (float*)wlds;
#pragma unroll
    for (int rt = 0; rt < 2; ++rt) {
        __syncthreads();
        float elp[4][4] = {}, erp[4][4] = {};
#pragma unroll
        for (int ct = 0; ct < CT; ++ct) {
            const int p = ct * 16 + l16;
            const int j = p % HS, h = p / HS;
            const bool valid = (j < HW);
            float alc = valid ? ldx(al, h * HW + j, bf) : 0.f;
            float arc = valid ? ldx(ar, h * HW + j, bf) : 0.f;
#pragma unroll
            for (int r = 0; r < 4; ++r) {
                float v = acc[rt][ct][r];
#pragma unroll
                for (int h2 = 0; h2 < 4; ++h2) {
                    elp[r][h2] += (h == h2) ? v * alc : 0.f;
                    erp[r][h2] += (h == h2) ? v * arc : 0.f;
                }
            }
        }
#pragma unroll
        for (int r = 0; r < 4; ++r)
#pragma unroll
            for (int h2 = 0; h2 < 4; ++h2) {
                int slot = (wave * 128) + (q * 32) + (r * 8) + (h2 * 2);
                red[slot * 16 + l16] = elp[r][h2];
                red[(slot + 1) * 16 + l16] = erp[r][h2];
            }
        __syncthreads();
#pragma unroll
        for (int pass = 0; pass < 2; ++pass) {
            int slot = tid + pass * 256;
            float sum = 0.f;
#pragma unroll
            for (int j = 0; j < 16; ++j) sum += red[slot * 16 + j];
            int which = slot & 1;
            int h2 = (slot >> 1) & 3;
            int r  = (slot >> 3) & 3;
            int qq = (slot >> 5) & 3;
            int wv = slot >> 7;
            int node = base + rt * 64 + wv * 16 + qq * 4 + r;
            if (node < N) {
                if (which == 0) el[(size_t)node * 4 + h2] = sum;
                else            er[(size_t)node * 4 + h2] = sum;
            }
        }
    }
}

// ---------- wave-autonomous agg, layers 0/1 (S=128, HS=32) ----------
template <bool RELU>
__global__ void __launch_bounds__(256) agg01_k(const float* __restrict__ el,
                                               const float* __restrict__ er,
                                               const bf16* __restrict__ fs,
                                               const int* __restrict__ rowptr,
                                               const unsigned short* __restrict__ col,
                                               bf16* __restrict__ out, int N) {
    const int wave = threadIdx.x >> 6, lane = threadIdx.x & 63;
    const int d = blockIdx.x * 4 + wave;
    __shared__ float wrow[4][16][4];
    __shared__ int   scol[4][16];
    if (d >= N) return;
    const int rs = rowptr[d], re = rowptr[d + 1];
    const int g = lane >> 4, lg = lane & 15;
    const int c0 = lg * 8;

    if (re == rs) {
        if (g == 0) *(uint4*)(out + (size_t)d * 128 + c0) = make_uint4(0, 0, 0, 0);
        return;
    }

    float4 er4 = *(const float4*)(er + (size_t)d * 4);
    float er_d[4] = {er4.x, er4.y, er4.z, er4.w};

    const int eh = lane >> 2;
    const int hh = lane & 3;
    const int h0 = lg >> 2;

    float acc[8] = {0, 0, 0, 0, 0, 0, 0, 0};
    float swp = 0.f;

    for (int cs = rs; cs < re; cs += 16) {
        int ne = min(16, re - cs);
        if (eh < ne) {
            int s = (int)col[cs + eh];
            if (hh == 0) scol[wave][eh] = s;
            float x = el[(size_t)s * 4 + hh] + er_d[hh];
            x = x >= 0.f ? x : 0.2f * x;
            float w = __expf(x);
            wrow[wave][eh][hh] = w;
            swp += w;
        }
#pragma unroll 4
        for (int e = g; e < ne; e += 4) {
            int s = scol[wave][e];
            float w = wrow[wave][e][h0];
            uint4 u = *(const uint4*)(fs + (size_t)s * 128 + c0);
            acc[0] += w * bl(u.x); acc[1] += w * bh(u.x);
            acc[2] += w * bl(u.y); acc[3] += w * bh(u.y);
            acc[4] += w * bl(u.z); acc[5] += w * bh(u.z);
            acc[6] += w * bl(u.w); acc[7] += w * bh(u.w);
        }
    }

#pragma unroll
    for (int k = 0; k < 8; ++k) {
        acc[k] += __shfl_xor(acc[k], 16);
        acc[k] += __shfl_xor(acc[k], 32);
    }
#pragma unroll
    for (int off = 4; off < 64; off <<= 1) swp += __shfl_xor(swp, off);
    float sh = __shfl(swp, h0);

    if (g == 0) {
        float inv = 1.0f / sh;
        float v[8];
#pragma unroll
        for (int k = 0; k < 8; ++k) {
            v[k] = acc[k] * inv;
            if (RELU) v[k] = fmaxf(v[k], 0.f);
        }
        uint4 o;
        o.x = (unsigned)f2b_bits(v[0]) | ((unsigned)f2b_bits(v[1]) << 16);
        o.y = (unsigned)f2b_bits(v[2]) | ((unsigned)f2b_bits(v[3]) << 16);
        o.z = (unsigned)f2b_bits(v[4]) | ((unsigned)f2b_bits(v[5]) << 16);
        o.w = (unsigned)f2b_bits(v[6]) | ((unsigned)f2b_bits(v[7]) << 16);
        *(uint4*)(out + (size_t)d * 128 + c0) = o;
    }
}

// ---------- layer-2 agg + fused head-mean + log_softmax -> d_out ----------
__global__ void __launch_bounds__(192) agg2_k(const float* __restrict__ el,
                                              const float* __restrict__ er,
                                              const bf16* __restrict__ fs,
                                              const int* __restrict__ rowptr,
                                              const unsigned short* __restrict__ col,
                                              void* __restrict__ out,
                                              const int* __restrict__ flag) {
    constexpr int HS = 48, S = 192, LPG = 24, TPB = 192;
    constexpr int NG = TPB / LPG;       // 8
    constexpr int CH = TPB / 4;         // 48
    constexpr int NW = TPB / 64;        // 3
    const int d = blockIdx.x;
    const int tid = threadIdx.x;
    const bool bf = (*flag != 0);
    const int rs = rowptr[d], re = rowptr[d + 1];

    __shared__ float wrow[CH][4];
    __shared__ int scol_s[CH];
    __shared__ float part[NG][S];
    __shared__ float red2[NW][4];
    __shared__ float sh_s[4];
    __shared__ float vout[S];

    if (re == rs) {
        if (tid < 47) {
            float r = -logf(47.f);
            if (bf) ((bf16*)out)[(size_t)d * 47 + tid] = __float2bfloat16(r);
            else    ((float*)out)[(size_t)d * 47 + tid] = r;
        }
        return;
    }

    float4 er4 = *(const float4*)(er + (size_t)d * 4);
    float er_d[4] = {er4.x, er4.y, er4.z, er4.w};

    const int g  = tid / LPG;
    const int lg = tid % LPG;
    const int c0 = lg * 8;
    const int h0 = c0 / HS;

    float acc[8] = {0, 0, 0, 0, 0, 0, 0, 0};
    float swpart = 0.f;

    for (int cs = rs; cs < re; cs += CH) {
        int ne = min(CH, re - cs);
        if (tid < ne * 4) {
            int j = tid >> 2, h = tid & 3;
            int s = (int)col[cs + j];
            if (h == 0) scol_s[j] = s;
            float x = el[(size_t)s * 4 + h] + er_d[h];
            x = x >= 0.f ? x : 0.2f * x;
            float w = __expf(x);
            wrow[j][h] = w;
            swpart += w;
        }
        __syncthreads();
#pragma unroll 4
        for (int e = g; e < ne; e += NG) {
            int s = scol_s[e];
            uint4 u = *(const uint4*)(fs + (size_t)s * S + c0);
            float w = wrow[e][h0];
            acc[0] += w * bl(u.x); acc[1] += w * bh(u.x);
            acc[2] += w * bl(u.y); acc[3] += w * bh(u.y);
            acc[4] += w * bl(u.z); acc[5] += w * bh(u.z);
            acc[6] += w * bl(u.w); acc[7] += w * bh(u.w);
        }
        __syncthreads();
    }

    float sw = swpart;
#pragma unroll
    for (int off = 4; off < 64; off <<= 1) sw += __shfl_xor(sw, off);
    const int wave = tid >> 6, lane = tid & 63;
    if (lane < 4) red2[wave][lane] = sw;
#pragma unroll
    for (int k = 0; k < 8; ++k) part[g][c0 + k] = acc[k];
    __syncthreads();
    if (tid < 4) {
        float s = 0.f;
#pragma unroll
        for (int w = 0; w < NW; ++w) s += red2[w][tid];
        sh_s[tid] = s;
    }
    __syncthreads();

    if (tid < S / 4) {
        int c = tid * 4;
        float4 v = make_float4(0, 0, 0, 0);
#pragma unroll
        for (int gg = 0; gg < NG; ++gg) {
            v.x += part[gg][c + 0]; v.y += part[gg][c + 1];
            v.z += part[gg][c + 2]; v.w += part[gg][c + 3];
        }
        float is = 1.0f / sh_s[c / HS];
        vout[c + 0] = v.x * is; vout[c + 1] = v.y * is;
        vout[c + 2] = v.z * is; vout[c + 3] = v.w * is;
    }
    __syncthreads();

    if (tid < 64) {
        int c = tid;
        float val = 0.f, vm = -INFINITY;
        if (c < 47) {
            val = 0.25f * (vout[c] + vout[48 + c] + vout[96 + c] + vout[144 + c]);
            vm = val;
        }
        float m = vm;
#pragma unroll
        for (int off = 32; off >= 1; off >>= 1) m = fmaxf(m, __shfl_xor(m, off));
        float ex = (c < 47) ? __expf(val - m) : 0.f;
        float s = ex;
#pragma unroll
        for (int off = 32; off >= 1; off >>= 1) s += __shfl_xor(s, off);
        if (c < 47) {
            float r = val - m - logf(s);
            if (bf) ((bf16*)out)[(size_t)d * 47 + c] = __float2bfloat16(r);
            else    ((float*)out)[(size_t)d * 47 + c] = r;
        }
    }
}

extern "C" void kernel_launch(void* const* d_in, const int* in_sizes, int n_in,
                              void* d_out, int out_size, void* d_ws, size_t ws_size,
                              hipStream_t stream) {
    const void* x   = d_in[0];
    const void* W0  = d_in[1];
    const void* al0 = d_in[2];
    const void* ar0 = d_in[3];
    const void* W1  = d_in[4];
    const void* al1 = d_in[5];
    const void* ar1 = d_in[6];
    const void* W2  = d_in[7];
    const void* al2 = d_in[8];
    const void* ar2 = d_in[9];
    const int* src  = (const int*)d_in[10];
    const int* dst  = (const int*)d_in[11];
    const int E = in_sizes[10];
    const int N = NN;

    bf16* fs    = (bf16*)d_ws;                      // N*192 bf16
    bf16* hb16  = fs + (size_t)N * 192;             // N*128 bf16
    bf16* xpad  = hb16 + (size_t)N * 128;           // N*128 bf16
    float* el   = (float*)(xpad + (size_t)N * 128); // N*4
    float* er   = el + (size_t)N * H;               // N*4
    int* rowptr = (int*)(er + (size_t)N * H);       // N+1
    int* deg    = rowptr + (N + 1);                 // N
    unsigned short* col16  = (unsigned short*)(deg + N);   // E u16
    unsigned short* slot16 = col16 + E;                    // E u16
    int* bsum   = (int*)(slot16 + E);               // 256
    int* boff   = bsum + 256;                       // 256
    int* flag   = boff + 256;                       // 1

    const int gN  = (N + 255) / 256;                // 196 blocks
    const int gE  = (E + 255) / 256;
    const int gG  = (N + 127) / 128;                // 391 gemm blocks
    const int gA  = (N + 3) / 4;                    // 12500 agg01 blocks

    detect_k<<<1, 256, 0, stream>>>(x, flag);
    xpad_k<<<(N * 128 + 255) / 256, 256, 0, stream>>>(x, xpad, flag, N * 128);

    // CSR build (graph identical for all 3 layers)
    hipMemsetAsync(deg, 0, (size_t)N * 4, stream);
    deg_k<<<gE, 256, 0, stream>>>(dst, deg, slot16, E);
    scan1_k<<<gN, 256, 0, stream>>>(deg, rowptr, bsum, N);
    scan2_k<<<1, 256, 0, stream>>>(bsum, boff, gN);
    scan3_k<<<gN, 256, 0, stream>>>(rowptr, boff, N, E);
    fill_k<<<gE, 256, 0, stream>>>(src, dst, rowptr, slot16, col16, E);

    // ---------------- Layer 0: W[100,128], HS=HW=32 ----------------
    gemm_k<100, 128, 128, 32, 32><<<gG, 256, 0, stream>>>(
        xpad, W0, al0, ar0, fs, el, er, flag, N);
    agg01_k<true><<<gA, 256, 0, stream>>>(el, er, fs, rowptr, col16, hb16, N);

    // ---------------- Layer 1: W[128,128], HS=HW=32 ----------------
    gemm_k<128, 128, 128, 32, 32><<<gG, 256, 0, stream>>>(
        hb16, W1, al1, ar1, fs, el, er, flag, N);
    agg01_k<true><<<gA, 256, 0, stream>>>(el, er, fs, rowptr, col16, hb16, N);

    // ---------------- Layer 2: W[128,188], HS=48, HW=47 (head-padded) ------
    gemm_k<128, 188, 192, 48, 47><<<gG, 256, 0, stream>>>(
        hb16, W2, al2, ar2, fs, el, er, flag, N);
    agg2_k<<<N, 192, 0, stream>>>(el, er, fs, rowptr, col16, d_out, flag);
}